// Round 11
// baseline (1109.064 us; speedup 1.0000x reference)
//
#include <hip/hip_runtime.h>
#include <math.h>

// PnPNystra attention, MFMA v10: TWO groups per 1024-thr block.
// Waves 0-7 -> group 2g, waves 8-15 -> group 2g+1; each group has its own
// v8-style 5-plane-pair LDS region (2 x 81920 B = 163840 B = full 160 KiB).
// Per-phase work doubles (2 independent matmuls) -> latency/drain overlap;
// phases-per-group halve. KM/KV stashed to og during pinv (v8 scheme).
// Numerics: split f16 (v ~= h + l/2048), 3x mfma_f32_16x16x32_f16, Z scaled 1024.
// G=4096 groups, N=256, d=64, L=64.

#define G_TOT 4096
#define TPB_R 256
#define TPB_M 1024
typedef _Float16 f16;
typedef __attribute__((ext_vector_type(2))) _Float16 f16x2;
typedef __attribute__((ext_vector_type(4))) _Float16 f16x4;
typedef __attribute__((ext_vector_type(8))) _Float16 f16x8;
typedef __attribute__((ext_vector_type(4))) float f32x4;
typedef __attribute__((ext_vector_type(16))) float f32x16;

#define SMEM_BYTES 163840   // 2 groups x 10 planes x 8192 B

#define LSCALE 2048.0f
#define LINV   (1.0f / 2048.0f)
#define ZS     1024.0f
#define ZINV   (1.0f / 1024.0f)

struct HL { f16 h, l; };
__device__ __forceinline__ HL split2(float v) {
    HL r;
    r.h = (f16)v;
    r.l = (f16)((v - (float)r.h) * LSCALE);
    return r;
}
__device__ __forceinline__ float join2(f16 h, f16 l) {
    return (float)h + (float)l * LINV;
}
__device__ __forceinline__ int swi(int r, int c) {
    return (r << 6) + (c ^ ((r & 7) << 3));
}
__device__ __forceinline__ float activ_f(float x) {
    return __expf(fminf(x, 5.0f)) + fmaxf(x - 5.0f, 0.0f);
}
__device__ __forceinline__ float activ_r(float x) {
    return expf(fminf(x, 5.0f)) + fmaxf(x - 5.0f, 0.0f);
}
__device__ __forceinline__ void split_w(f16* Ph, f16* Pl, int r, int c, float v) {
    HL s = split2(v);
    const int o = swi(r, c);
    Ph[o] = s.h;
    Pl[o] = s.l;
}
__device__ __forceinline__ f16x2 mk2(f16 a, f16 b) { f16x2 r; r[0]=a; r[1]=b; return r; }
__device__ __forceinline__ f16x4 mk4(f16 a, f16 b, f16 c, f16 d) { f16x4 r; r[0]=a;r[1]=b;r[2]=c;r[3]=d; return r; }
__device__ __forceinline__ f32x4 z4() { f32x4 z = {0.f,0.f,0.f,0.f}; return z; }
__device__ __forceinline__ f32x16 z16() {
    f32x16 z;
#pragma unroll
    for (int i = 0; i < 16; ++i) z[i] = 0.f;
    return z;
}

struct Frag { f16x8 h[2], l[2]; };

__device__ __forceinline__ Frag ld_frag(const f16* __restrict__ Ph,
                                        const f16* __restrict__ Pl,
                                        int row, int kg) {
    Frag f;
    const int base = row << 6, x = (row & 7) << 3;
#pragma unroll
    for (int s = 0; s < 2; ++s) {
        const int o = base + ((((s << 5) + (kg << 3))) ^ x);
        f.h[s] = *(const f16x8*)(Ph + o);
        f.l[s] = *(const f16x8*)(Pl + o);
    }
    return f;
}

// A-frag built straight from a global f32 row (no LDS staging)
__device__ __forceinline__ Frag mk_gfrag(const float* __restrict__ row, int kg) {
    Frag f;
#pragma unroll
    for (int s = 0; s < 2; ++s) {
        const float* p = row + (s << 5) + (kg << 3);
        float4 a = *(const float4*)p;
        float4 b = *(const float4*)(p + 4);
        HL s0 = split2(a.x), s1 = split2(a.y), s2 = split2(a.z), s3 = split2(a.w);
        HL s4 = split2(b.x), s5 = split2(b.y), s6 = split2(b.z), s7 = split2(b.w);
        f16x8 h, l;
        h[0]=s0.h; h[1]=s1.h; h[2]=s2.h; h[3]=s3.h; h[4]=s4.h; h[5]=s5.h; h[6]=s6.h; h[7]=s7.h;
        l[0]=s0.l; l[1]=s1.l; l[2]=s2.l; l[3]=s3.l; l[4]=s4.l; l[5]=s5.l; l[6]=s6.l; l[7]=s7.l;
        f.h[s] = h; f.l[s] = l;
    }
    return f;
}

__device__ __forceinline__ f32x4 mm16_rr(const Frag& A, const Frag& B, f32x4 acc) {
    f32x4 ax1 = z4(), ax2 = z4();
#pragma unroll
    for (int s = 0; s < 2; ++s) {
        acc = __builtin_amdgcn_mfma_f32_16x16x32_f16(A.h[s], B.h[s], acc, 0, 0, 0);
        ax1 = __builtin_amdgcn_mfma_f32_16x16x32_f16(A.h[s], B.l[s], ax1, 0, 0, 0);
        ax2 = __builtin_amdgcn_mfma_f32_16x16x32_f16(A.l[s], B.h[s], ax2, 0, 0, 0);
    }
    acc += (ax1 + ax2) * LINV;
    return acc;
}

__device__ __forceinline__ void wfrag_rm(f16* Ph, f16* Pl, int Rb, int C, const float* v) {
#pragma unroll
    for (int m = 0; m < 4; ++m) split_w(Ph, Pl, Rb + m, C, v[m]);
}
__device__ __forceinline__ void wfrag_t(f16* Ph, f16* Pl, int Rb, int C, const float* v) {
    const int o = swi(C, Rb);
    HL s0 = split2(v[0]), s1 = split2(v[1]), s2 = split2(v[2]), s3 = split2(v[3]);
    *(f16x4*)(Ph + o) = mk4(s0.h, s1.h, s2.h, s3.h);
    *(f16x4*)(Pl + o) = mk4(s0.l, s1.l, s2.l, s3.l);
}

// ---- staging helpers (per-group: tl in [0,512)) ----
__device__ __forceinline__ void wr_rm_f(float4 vv, f16* Ph, f16* Pl, int f) {
    const int r = f >> 4, c4 = (f & 15) << 2;
    const int o = swi(r, c4);
    HL s0 = split2(vv.x), s1 = split2(vv.y), s2 = split2(vv.z), s3 = split2(vv.w);
    *(f16x4*)(Ph + o) = mk4(s0.h, s1.h, s2.h, s3.h);
    *(f16x4*)(Pl + o) = mk4(s0.l, s1.l, s2.l, s3.l);
}
__device__ __forceinline__ void ld_vt(const float* __restrict__ src, int t,
                                      float4& va, float4& vb) {
    const int n0 = (t >> 4) << 1, e0 = (t & 15) << 2;
    va = *(const float4*)(src + (size_t)n0 * 64 + e0);
    vb = *(const float4*)(src + (size_t)(n0 + 1) * 64 + e0);
}
__device__ __forceinline__ void wr_vt(float4 va, float4 vb, f16* Ph, f16* Pl, int t) {
    const int n0 = (t >> 4) << 1, e0 = (t & 15) << 2;
    const float* a = (const float*)&va;
    const float* b = (const float*)&vb;
#pragma unroll
    for (int j = 0; j < 4; ++j) {
        HL sa = split2(a[j]), sb = split2(b[j]);
        const int o = swi(e0 + j, n0);
        *(f16x2*)(Ph + o) = mk2(sa.h, sb.h);
        *(f16x2*)(Pl + o) = mk2(sa.l, sb.l);
    }
}
__device__ __forceinline__ void pool_global512(const float* __restrict__ src,
                                               f16* Ph, f16* Pl, int t) {
    const int L = t >> 3, d0 = (t & 7) << 3;
    const int nb = ((L >> 3) << 5) + ((L & 7) << 1);
    const float* p = src + (size_t)nb * 64 + d0;
    float4 a0 = *(const float4*)p;           float4 a1 = *(const float4*)(p + 4);
    float4 b0 = *(const float4*)(p + 64);    float4 b1 = *(const float4*)(p + 68);
    float4 c0 = *(const float4*)(p + 1024);  float4 c1 = *(const float4*)(p + 1028);
    float4 d0_ = *(const float4*)(p + 1088); float4 d1 = *(const float4*)(p + 1092);
    HL s0 = split2(0.25f * (a0.x + b0.x + c0.x + d0_.x));
    HL s1 = split2(0.25f * (a0.y + b0.y + c0.y + d0_.y));
    HL s2 = split2(0.25f * (a0.z + b0.z + c0.z + d0_.z));
    HL s3 = split2(0.25f * (a0.w + b0.w + c0.w + d0_.w));
    HL s4 = split2(0.25f * (a1.x + b1.x + c1.x + d1.x));
    HL s5 = split2(0.25f * (a1.y + b1.y + c1.y + d1.y));
    HL s6 = split2(0.25f * (a1.z + b1.z + c1.z + d1.z));
    HL s7 = split2(0.25f * (a1.w + b1.w + c1.w + d1.w));
    const int o = swi(L, d0);
    *(f16x4*)(Ph + o)     = mk4(s0.h, s1.h, s2.h, s3.h);
    *(f16x4*)(Ph + o + 4) = mk4(s4.h, s5.h, s6.h, s7.h);
    *(f16x4*)(Pl + o)     = mk4(s0.l, s1.l, s2.l, s3.l);
    *(f16x4*)(Pl + o + 4) = mk4(s4.l, s5.l, s6.l, s7.l);
}
__device__ __forceinline__ void pool_lds512(const f16* Kh, const f16* Kl,
                                            f16* Ph, f16* Pl, int t, int tt) {
    const int ll = t >> 5, d0 = (t & 31) << 1;
    const int rb = ((ll >> 3) << 5) + ((ll & 7) << 1);
    float s0 = 0.f, s1 = 0.f;
#pragma unroll
    for (int rr = 0; rr < 4; ++rr) {
        const int r = rb + (rr & 1) + ((rr >> 1) << 4);
        const int o = swi(r, d0);
        f16x2 h = *(const f16x2*)(Kh + o);
        f16x2 l = *(const f16x2*)(Kl + o);
        s0 += join2(h[0], l[0]);
        s1 += join2(h[1], l[1]);
    }
    const int L = (tt << 4) + ll;
    HL p0 = split2(0.25f * s0), p1 = split2(0.25f * s1);
    const int o = swi(L, d0);
    *(f16x2*)(Ph + o) = mk2(p0.h, p1.h);
    *(f16x2*)(Pl + o) = mk2(p0.l, p1.l);
}

// ---- k_reduce helpers (unchanged) ----
__device__ __forceinline__ f32x16 mm64q(const f16* __restrict__ Ah, const f16* __restrict__ Al,
                                        const f16* __restrict__ Bh, const f16* __restrict__ Bl,
                                        int lane, int wr, int wc, f32x16 acc) {
    const int cl = lane & 31, hh = lane >> 5;
    const int ar = (wr << 5) + cl, br = (wc << 5) + cl;
    const int abase = ar << 6, axor = (ar & 7) << 3;
    const int bbase = br << 6, bxor = (br & 7) << 3;
    f32x16 ax1 = z16();
    f32x16 ax2 = z16();
#pragma unroll
    for (int ks = 0; ks < 4; ++ks) {
        const int k0 = (ks << 4) + (hh << 3);
        const int ao = abase + (k0 ^ axor);
        const int bo = bbase + (k0 ^ bxor);
        f16x8 a_h = *(const f16x8*)(Ah + ao);
        f16x8 a_l = *(const f16x8*)(Al + ao);
        f16x8 b_h = *(const f16x8*)(Bh + bo);
        f16x8 b_l = *(const f16x8*)(Bl + bo);
        acc = __builtin_amdgcn_mfma_f32_32x32x16_f16(a_h, b_h, acc, 0, 0, 0);
        ax1 = __builtin_amdgcn_mfma_f32_32x32x16_f16(a_h, b_l, ax1, 0, 0, 0);
        ax2 = __builtin_amdgcn_mfma_f32_32x32x16_f16(a_l, b_h, ax2, 0, 0, 0);
    }
    acc += (ax1 + ax2) * LINV;
    return acc;
}
__device__ __forceinline__ void pool_global_r(const float* __restrict__ src,
                                              f16* Ph, f16* Pl, int t) {
    const int ll = t >> 4, d0 = (t & 15) << 2;
    const int rb = ((ll >> 3) << 5) + ((ll & 7) << 1);
#pragma unroll
    for (int tt = 0; tt < 4; ++tt) {
        const float* p = src + (size_t)((tt << 6) + rb) * 64 + d0;
        float4 a = *(const float4*)p;
        float4 b = *(const float4*)(p + 64);
        float4 c = *(const float4*)(p + 1024);
        float4 d = *(const float4*)(p + 1088);
        const int L = (tt << 4) + ll;
        split_w(Ph, Pl, L, d0 + 0, 0.25f * (a.x + b.x + c.x + d.x));
        split_w(Ph, Pl, L, d0 + 1, 0.25f * (a.y + b.y + c.y + d.y));
        split_w(Ph, Pl, L, d0 + 2, 0.25f * (a.z + b.z + c.z + d.z));
        split_w(Ph, Pl, L, d0 + 3, 0.25f * (a.w + b.w + c.w + d.w));
    }
}

#define WAVE_SUM32(v)            \
    v += __shfl_xor(v, 1);       \
    v += __shfl_xor(v, 2);       \
    v += __shfl_xor(v, 4);       \
    v += __shfl_xor(v, 8);       \
    v += __shfl_xor(v, 16);

__global__ void k_init(float* ws) {
    if (threadIdx.x < 2) ws[threadIdx.x] = 0.0f;
}

__global__ __launch_bounds__(TPB_R) void k_reduce(const float* __restrict__ q,
                                                  const float* __restrict__ k,
                                                  float* __restrict__ ws) {
    __shared__ f16 pls[4 * 4096];
    __shared__ float rowS[64], colS[64];
    const int t = threadIdx.x, g = blockIdx.x;
    const int lane = t & 63, wv = t >> 6, wr = wv >> 1, wc = wv & 1;
    const int cl = lane & 31, hh = lane >> 5;
    if (t < 64) rowS[t] = 0.f;
    else if (t < 128) colS[t - 64] = 0.f;
    pool_global_r(q + (size_t)g * 16384, pls, pls + 4096, t);
    pool_global_r(k + (size_t)g * 16384, pls + 8192, pls + 12288, t);
    __syncthreads();
    f32x16 a = mm64q(pls, pls + 4096, pls + 8192, pls + 12288, lane, wr, wc, z16());
    float colp = 0.f;
#pragma unroll
    for (int m = 0; m < 16; ++m) {
        float x = activ_r(a[m]);
        const int R = (wr << 5) + (m & 3) + ((m >> 2) << 3) + (hh << 2);
        float vs = x;
        WAVE_SUM32(vs)
        if (cl == 0) atomicAdd(&rowS[R], vs);
        colp += x;
    }
    colp += __shfl_xor(colp, 32);
    if (hh == 0) atomicAdd(&colS[(wc << 5) + cl], colp);
    __syncthreads();
    if (t < 64) {
        float vmx = rowS[t];
        for (int off = 1; off < 64; off <<= 1) vmx = fmaxf(vmx, __shfl_xor(vmx, off));
        if (t == 0) atomicMax((int*)ws, __float_as_int(vmx));
    } else if (t < 128) {
        float vmx = colS[t - 64];
        for (int off = 1; off < 64; off <<= 1) vmx = fmaxf(vmx, __shfl_xor(vmx, off));
        if (t == 64) atomicMax(((int*)ws) + 1, __float_as_int(vmx));
    }
}

// ============================ k_main (v10) ============================
// Two groups per block: waves 0-7 -> group 2*blk, waves 8-15 -> group 2*blk+1.
// Per group: v8's 5-pair choreography in its own 81920 B LDS region.
__global__ __launch_bounds__(TPB_M, 4) void k_main(const float* __restrict__ q,
                                                   const float* __restrict__ k,
                                                   const float* __restrict__ v,
                                                   const float* __restrict__ ws,
                                                   float* __restrict__ out) {
    extern __shared__ f16 smu[];
    const int t = threadIdx.x;
    const int grp = t >> 9, tl = t & 511;
    const int g = (blockIdx.x << 1) + grp;
    f16* B0 = smu + grp * 40960;     // 40960 f16 = 81920 B per group
    f16* P1h = B0;            f16* P1l = B0 + 4096;
    f16* P2h = B0 + 8192;     f16* P2l = B0 + 12288;
    f16* P3h = B0 + 16384;    f16* P3l = B0 + 20480;
    f16* P4h = B0 + 24576;    f16* P4l = B0 + 28672;
    f16* P5h = B0 + 32768;    f16* P5l = B0 + 36864;
    float* P5f = (float*)P5h;   // f32 view: kv1 / den partials (2x64)

    const int lane = t & 63, wg = (t >> 6) & 7;   // wave-in-group 0..7
    const int ti = wg & 3, tjh = wg >> 2;
    const int fr = lane & 15, kg = lane >> 4;
    const int arow = (ti << 4) + fr;
    const int brow0 = (tjh << 5) + fr, brow1 = brow0 + 16;
    const int C0 = brow0, C1 = brow1;
    const int Rb = (ti << 4) + (kg << 2);
    const float* Gq = q + (size_t)g * 16384;
    const float* Gk = k + (size_t)g * 16384;
    const float* Gv = v + (size_t)g * 16384;
    float* og = out + (size_t)g * 16384;

    // ---- prologue: QM->P5; K0->P1; V0t->P2 ----
    pool_global512(Gq, P5h, P5l, tl);
    {
        float4 k0a = *(const float4*)(Gk + (size_t)tl * 4);
        float4 k0b = *(const float4*)(Gk + (size_t)(tl + 512) * 4);
        float4 va0, vb0; ld_vt(Gv, tl, va0, vb0);
        wr_rm_f(k0a, P1h, P1l, tl);
        wr_rm_f(k0b, P1h, P1l, tl + 512);
        wr_vt(va0, vb0, P2h, P2l, tl);
    }
    __syncthreads();

    Frag fQM = ld_frag(P5h, P5l, arow, kg);

    // ---- phase E: KV = activ(QM@K^T)@V ; pool KM ; kv1 partials in regs ----
    f32x4 kva0 = z4(), kva1 = z4();
    float kv1p[4] = {0.f, 0.f, 0.f, 0.f};
    for (int tt = 0; tt < 4; ++tt) {
        f16* ch = (tt & 1) ? P5h : P2h; f16* cl_ = (tt & 1) ? P5l : P2l;
        f16* nh = (tt & 1) ? P2h : P5h; f16* nl = (tt & 1) ? P2l : P5l;
        float4 krA, krB, vaN, vbN;
        if (tt < 3) {
            const float* nk = Gk + (size_t)(tt + 1) * 4096;
            krA = *(const float4*)(nk + (size_t)tl * 4);
            krB = *(const float4*)(nk + (size_t)(tl + 512) * 4);
            ld_vt(Gv + (size_t)(tt + 1) * 4096, tl, vaN, vbN);
        }
        pool_lds512(P1h, P1l, P4h, P4l, tl, tt);
        {
            Frag bK0 = ld_frag(P1h, P1l, brow0, kg);
            Frag bK1 = ld_frag(P1h, P1l, brow1, kg);
            f32x4 s0 = mm16_rr(fQM, bK0, z4());
            f32x4 s1 = mm16_rr(fQM, bK1, z4());
            float sv0[4], sv1[4];
#pragma unroll
            for (int m = 0; m < 4; ++m) {
                sv0[m] = activ_f(s0[m]);
                sv1[m] = activ_f(s1[m]);
                float vs = sv0[m] + sv1[m];
                vs += __shfl_xor(vs, 1); vs += __shfl_xor(vs, 2);
                vs += __shfl_xor(vs, 4); vs += __shfl_xor(vs, 8);
                kv1p[m] += vs;
            }
            wfrag_rm(P3h, P3l, Rb, C0, sv0);
            wfrag_rm(P3h, P3l, Rb, C1, sv1);
        }
        __syncthreads();
        {
            Frag aS = ld_frag(P3h, P3l, arow, kg);
            Frag bV0 = ld_frag(ch, cl_, brow0, kg);
            Frag bV1 = ld_frag(ch, cl_, brow1, kg);
            kva0 = mm16_rr(aS, bV0, kva0);
            kva1 = mm16_rr(aS, bV1, kva1);
        }
        if (tt < 3) {
            wr_rm_f(krA, P1h, P1l, tl);
            wr_rm_f(krB, P1h, P1l, tl + 512);
            wr_vt(vaN, vbN, nh, nl, tl);
        }
        __syncthreads();
    }

    // ---- phase B: stash KM,KV -> og ; X = activ(QM@KM^T) -> P1 ; Z-init ----
    {
        const unsigned* sKM = (const unsigned*)P4h;
        unsigned* dKM = (unsigned*)og;
#pragma unroll
        for (int i = 0; i < 8; ++i) dKM[tl + (i << 9)] = sKM[tl + (i << 9)];
#pragma unroll
        for (int m = 0; m < 4; ++m) {
            og[4096 + (size_t)(Rb + m) * 64 + C0] = kva0[m];
            og[4096 + (size_t)(Rb + m) * 64 + C1] = kva1[m];
        }
        Frag bKM0 = ld_frag(P4h, P4l, brow0, kg);
        Frag bKM1 = ld_frag(P4h, P4l, brow1, kg);
        f32x4 x0 = mm16_rr(fQM, bKM0, z4());
        f32x4 x1 = mm16_rr(fQM, bKM1, z4());
        const float scale = ZS / (ws[0] * ws[1] + 1e-15f);
        float xv0[4], xv1[4], zv0[4], zv1[4];
#pragma unroll
        for (int m = 0; m < 4; ++m) {
            xv0[m] = activ_f(x0[m]); zv0[m] = xv0[m] * scale;
            xv1[m] = activ_f(x1[m]); zv1[m] = xv1[m] * scale;
        }
        wfrag_rm(P1h, P1l, Rb, C0, xv0);  wfrag_rm(P1h, P1l, Rb, C1, xv1);   // X
        wfrag_t (P2h, P2l, Rb, C0, zv0);  wfrag_t (P2h, P2l, Rb, C1, zv1);   // Zr
        wfrag_rm(P3h, P3l, Rb, C0, zv0);  wfrag_rm(P3h, P3l, Rb, C1, zv1);   // Zt
    }
    __syncthreads();

    // ---- B2: cache fX ; kv1 partials -> P5f[tjh*64 + R] ----
    Frag fX = ld_frag(P1h, P1l, arow, kg);
    if (fr == 0) {
#pragma unroll
        for (int m = 0; m < 4; ++m) P5f[(tjh << 6) + Rb + m] = kv1p[m];
    }
    __syncthreads();

    // ---- phase D: 6 Newton-Schulz iterations, 5-pair rotation ----
    f16 *r0h = P2h, *r0l = P2l;
    f16 *r1h = P4h, *r1l = P4l;
    f16 *r2h = P5h, *r2l = P5l;
    float kvC0 = 0.f, kvC1 = 0.f;
#pragma unroll
    for (int it = 0; it < 6; ++it) {
        Frag bz0 = ld_frag(P3h, P3l, brow0, kg);
        Frag bz1 = ld_frag(P3h, P3l, brow1, kg);
        f32x4 a10 = mm16_rr(fX, bz0, z4());
        f32x4 a11 = mm16_rr(fX, bz1, z4());
        if (it == 0) {
            kvC0 = P5f[C0] + P5f[64 + C0];
            kvC1 = P5f[C1] + P5f[64 + C1];
        }
        float t1k0[4], t1k1[4];
#pragma unroll
        for (int m = 0; m < 4; ++m) { t1k0[m] = a10[m] * ZINV; t1k1[m] = a11[m] * ZINV; }
        wfrag_rm(P1h, P1l, Rb, C0, t1k0);  wfrag_rm(P1h, P1l, Rb, C1, t1k1);
        wfrag_t (r1h, r1l, Rb, C0, t1k0);  wfrag_t (r1h, r1l, Rb, C1, t1k1);
        __syncthreads();
        Frag aT1 = ld_frag(P1h, P1l, arow, kg);
        Frag bT10 = ld_frag(r1h, r1l, brow0, kg);
        Frag bT11 = ld_frag(r1h, r1l, brow1, kg);
        f32x4 a20 = mm16_rr(aT1, bT10, z4());
        f32x4 a21 = mm16_rr(aT1, bT11, z4());
        float t2k0[4], t2k1[4];
#pragma unroll
        for (int m = 0; m < 4; ++m) { t2k0[m] = a20[m]; t2k1[m] = a21[m]; }
        wfrag_rm(r2h, r2l, Rb, C0, t2k0);  wfrag_rm(r2h, r2l, Rb, C1, t2k1);
        __syncthreads();
        Frag aT2 = ld_frag(r2h, r2l, arow, kg);
        f32x4 a30 = mm16_rr(aT2, bT10, z4());
        f32x4 a31 = mm16_rr(aT2, bT11, z4());
        float ov0[4], ov1[4];
#pragma unroll
        for (int m = 0; m < 4; ++m) {
            const int R = Rb + m;
            ov0[m] = ((R == C0) ? 13.f : 0.f) - 15.f * t1k0[m] + 7.f * t2k0[m] - a30[m];
            ov1[m] = ((R == C1) ? 13.f : 0.f) - 15.f * t1k1[m] + 7.f * t2k1[m] - a31[m];
        }
        wfrag_t(P1h, P1l, Rb, C0, ov0);  wfrag_t(P1h, P1l, Rb, C1, ov1);
        __syncthreads();
        Frag aZ = ld_frag(r0h, r0l, arow, kg);
        Frag bO0 = ld_frag(P1h, P1l, brow0, kg);
        Frag bO1 = ld_frag(P1h, P1l, brow1, kg);
        f32x4 a40 = mm16_rr(aZ, bO0, z4());
        f32x4 a41 = mm16_rr(aZ, bO1, z4());
        float zk0[4], zk1[4];
#pragma unroll
        for (int m = 0; m < 4; ++m) { zk0[m] = 0.25f * a40[m]; zk1[m] = 0.25f * a41[m]; }
        wfrag_rm(r1h, r1l, Rb, C0, zk0);  wfrag_rm(r1h, r1l, Rb, C1, zk1);
        wfrag_t (P3h, P3l, Rb, C0, zk0);  wfrag_t (P3h, P3l, Rb, C1, zk1);
        __syncthreads();
        f16 *th, *tlp;
        th = r0h; tlp = r0l;
        r0h = r1h; r0l = r1l;
        r1h = r2h; r1l = r2l;
        r2h = th;  r2l = tlp;
    }
    // final Zt = P3

    // ---- F reload: KM og -> P1 (raw), KV og -> P4 as KV^T (B-layout) ----
    {
        const unsigned* sKM = (const unsigned*)og;
        unsigned* dKM = (unsigned*)P1h;
#pragma unroll
        for (int i = 0; i < 8; ++i) dKM[tl + (i << 9)] = sKM[tl + (i << 9)];
#pragma unroll
        for (int i = 0; i < 2; ++i) {
            const int f = tl + (i << 9);
            float4 kvv = *(const float4*)(og + 4096 + (size_t)f * 4);
            const int l = f >> 4, e0 = (f & 15) << 2;
            split_w(P4h, P4l, e0 + 0, l, kvv.x);
            split_w(P4h, P4l, e0 + 1, l, kvv.y);
            split_w(P4h, P4l, e0 + 2, l, kvv.z);
            split_w(P4h, P4l, e0 + 3, l, kvv.w);
        }
    }
    __syncthreads();

    // ---- phase F: out = (activ(q@KM^T) @ Z @ KV) / den ; 4 q-tiles ----
    for (int tt = 0; tt < 4; ++tt) {
        {
            Frag aQ = mk_gfrag(Gq + (size_t)((tt << 6) + arow) * 64, kg);
            Frag bKM0 = ld_frag(P1h, P1l, brow0, kg);
            Frag bKM1 = ld_frag(P1h, P1l, brow1, kg);
            f32x4 q0 = mm16_rr(aQ, bKM0, z4());
            f32x4 q1 = mm16_rr(aQ, bKM1, z4());
            float qv0[4], qv1[4];
#pragma unroll
            for (int m = 0; m < 4; ++m) { qv0[m] = activ_f(q0[m]); qv1[m] = activ_f(q1[m]); }
            wfrag_rm(P5h, P5l, Rb, C0, qv0);
            wfrag_rm(P5h, P5l, Rb, C1, qv1);
        }
        __syncthreads();
        float dp[4];
        {
            Frag aK = ld_frag(P5h, P5l, arow, kg);
            Frag bZt0 = ld_frag(P3h, P3l, brow0, kg);
            Frag bZt1 = ld_frag(P3h, P3l, brow1, kg);
            f32x4 w0 = mm16_rr(aK, bZt0, z4());
            f32x4 w1 = mm16_rr(aK, bZt1, z4());
            float wv0[4], wv1[4];
#pragma unroll
            for (int m = 0; m < 4; ++m) {
                wv0[m] = w0[m] * ZINV;
                wv1[m] = w1[m] * ZINV;
                float d_ = wv0[m] * kvC0 + wv1[m] * kvC1;
                d_ += __shfl_xor(d_, 1); d_ += __shfl_xor(d_, 2);
                d_ += __shfl_xor(d_, 4); d_ += __shfl_xor(d_, 8);
                dp[m] = d_;
            }
            wfrag_rm(P2h, P2l, Rb, C0, wv0);
            wfrag_rm(P2h, P2l, Rb, C1, wv1);
        }
        __syncthreads();
        if (fr == 0) {
#pragma unroll
            for (int m = 0; m < 4; ++m) P5f[(tjh << 6) + Rb + m] = dp[m];
        }
        __syncthreads();
        {
            Frag aW = ld_frag(P2h, P2l, arow, kg);
            Frag bKV0 = ld_frag(P4h, P4l, brow0, kg);
            Frag bKV1 = ld_frag(P4h, P4l, brow1, kg);
            f32x4 p0 = mm16_rr(aW, bKV0, z4());
            f32x4 p1 = mm16_rr(aW, bKV1, z4());
#pragma unroll
            for (int m = 0; m < 4; ++m) {
                const int R = Rb + m;
                const float den = P5f[R] + P5f[64 + R];
                const float inv = 1.0f / (den + 1e-12f);
                og[(size_t)((tt << 6) + R) * 64 + C0] = p0[m] * inv;
                og[(size_t)((tt << 6) + R) * 64 + C1] = p1[m] * inv;
            }
        }
        __syncthreads();
    }
}

extern "C" void kernel_launch(void* const* d_in, const int* in_sizes, int n_in,
                              void* d_out, int out_size, void* d_ws, size_t ws_size,
                              hipStream_t stream) {
    const float* q = (const float*)d_in[0];
    const float* k = (const float*)d_in[1];
    const float* v = (const float*)d_in[2];
    float* out = (float*)d_out;
    float* ws  = (float*)d_ws;
    (void)in_sizes; (void)n_in; (void)out_size; (void)ws_size;

    hipFuncSetAttribute((const void*)k_main,
                        hipFuncAttributeMaxDynamicSharedMemorySize, SMEM_BYTES);

    k_init<<<1, 64, 0, stream>>>(ws);
    k_reduce<<<G_TOT, TPB_R, 0, stream>>>(q, k, ws);
    k_main<<<G_TOT / 2, TPB_M, SMEM_BYTES, stream>>>(q, k, v, ws, out);
}

// Round 12
// 794.288 us; speedup vs baseline: 1.3963x; 1.3963x over previous
//
#include <hip/hip_runtime.h>
#include <math.h>

// PnPNystra attention, MFMA v11 = v5 (715us champion) + VALU-diet:
//  - kv1 row-sums via MFMA ones-Frag (replaces shuffle+atomicAdd in E)
//  - den via MFMA kv1-Frag (replaces shuffle+atomicAdd in F)
//  - mm16 merge uses 2 accumulator chains (acc, ax) instead of 3
//  - F reads q via register-prefetched global A-frags (no q staging)
// Numerics: split f16 (v ~= h + l/2048), 3x mfma_f32_16x16x32_f16, Z scaled 1024.
// G=4096 groups, N=256, d=64, L=64. 1024 thr / 16 waves, 16 LDS planes.

#define G_TOT 4096
#define TPB_R 256
#define TPB_M 1024
typedef _Float16 f16;
typedef __attribute__((ext_vector_type(2))) _Float16 f16x2;
typedef __attribute__((ext_vector_type(4))) _Float16 f16x4;
typedef __attribute__((ext_vector_type(8))) _Float16 f16x8;
typedef __attribute__((ext_vector_type(4))) float f32x4;
typedef __attribute__((ext_vector_type(16))) float f32x16;

#define NPLANES 16
#define SMEM_BYTES (NPLANES * 4096 * 2 + 64 * 4)  // 131328 B

#define LSCALE 2048.0f
#define LINV   (1.0f / 2048.0f)
#define ZS     1024.0f
#define ZINV   (1.0f / 1024.0f)

struct HL { f16 h, l; };
__device__ __forceinline__ HL split2(float v) {
    HL r;
    r.h = (f16)v;
    r.l = (f16)((v - (float)r.h) * LSCALE);
    return r;
}
__device__ __forceinline__ float join2(f16 h, f16 l) {
    return (float)h + (float)l * LINV;
}
__device__ __forceinline__ int swi(int r, int c) {
    return (r << 6) + (c ^ ((r & 7) << 3));
}
__device__ __forceinline__ float activ_f(float x) {
    return __expf(fminf(x, 5.0f)) + fmaxf(x - 5.0f, 0.0f);
}
__device__ __forceinline__ float activ_r(float x) {
    return expf(fminf(x, 5.0f)) + fmaxf(x - 5.0f, 0.0f);
}
__device__ __forceinline__ void split_w(f16* Ph, f16* Pl, int r, int c, float v) {
    HL s = split2(v);
    const int o = swi(r, c);
    Ph[o] = s.h;
    Pl[o] = s.l;
}
__device__ __forceinline__ f16x2 mk2(f16 a, f16 b) { f16x2 r; r[0]=a; r[1]=b; return r; }
__device__ __forceinline__ f16x4 mk4(f16 a, f16 b, f16 c, f16 d) { f16x4 r; r[0]=a;r[1]=b;r[2]=c;r[3]=d; return r; }
__device__ __forceinline__ f32x4 z4() { f32x4 z = {0.f,0.f,0.f,0.f}; return z; }
__device__ __forceinline__ f32x16 z16() {
    f32x16 z;
#pragma unroll
    for (int i = 0; i < 16; ++i) z[i] = 0.f;
    return z;
}

struct Frag { f16x8 h[2], l[2]; };

__device__ __forceinline__ Frag ld_frag(const f16* __restrict__ Ph,
                                        const f16* __restrict__ Pl,
                                        int row, int kg) {
    Frag f;
    const int base = row << 6, x = (row & 7) << 3;
#pragma unroll
    for (int s = 0; s < 2; ++s) {
        const int o = base + ((((s << 5) + (kg << 3))) ^ x);
        f.h[s] = *(const f16x8*)(Ph + o);
        f.l[s] = *(const f16x8*)(Pl + o);
    }
    return f;
}

// 3-term split matmul, 2 accumulator chains (acc, ax)
__device__ __forceinline__ f32x4 mm16_rr(const Frag& A, const Frag& B, f32x4 acc) {
    f32x4 ax = z4();
#pragma unroll
    for (int s = 0; s < 2; ++s) {
        acc = __builtin_amdgcn_mfma_f32_16x16x32_f16(A.h[s], B.h[s], acc, 0, 0, 0);
        ax  = __builtin_amdgcn_mfma_f32_16x16x32_f16(A.h[s], B.l[s], ax, 0, 0, 0);
        ax  = __builtin_amdgcn_mfma_f32_16x16x32_f16(A.l[s], B.h[s], ax, 0, 0, 0);
    }
    acc += ax * LINV;
    return acc;
}

__device__ __forceinline__ void wfrag_rm(f16* Ph, f16* Pl, int Rb, int C, const float* v) {
#pragma unroll
    for (int m = 0; m < 4; ++m) split_w(Ph, Pl, Rb + m, C, v[m]);
}
__device__ __forceinline__ void wfrag_t(f16* Ph, f16* Pl, int Rb, int C, const float* v) {
    const int o = swi(C, Rb);
    HL s0 = split2(v[0]), s1 = split2(v[1]), s2 = split2(v[2]), s3 = split2(v[3]);
    *(f16x4*)(Ph + o) = mk4(s0.h, s1.h, s2.h, s3.h);
    *(f16x4*)(Pl + o) = mk4(s0.l, s1.l, s2.l, s3.l);
}

// ---- staging helpers (1024 threads) ----
__device__ __forceinline__ void wr_rm(float4 vv, f16* Ph, f16* Pl, int t) {
    const int r = t >> 4, c4 = (t & 15) << 2;
    const int o = swi(r, c4);
    HL s0 = split2(vv.x), s1 = split2(vv.y), s2 = split2(vv.z), s3 = split2(vv.w);
    *(f16x4*)(Ph + o) = mk4(s0.h, s1.h, s2.h, s3.h);
    *(f16x4*)(Pl + o) = mk4(s0.l, s1.l, s2.l, s3.l);
}
__device__ __forceinline__ void ld_vt(const float* __restrict__ src, int t,
                                      float2& va, float2& vb) {
    const int n0 = (t >> 5) << 1, e0 = (t & 31) << 1;
    va = *(const float2*)(src + (size_t)n0 * 64 + e0);
    vb = *(const float2*)(src + (size_t)(n0 + 1) * 64 + e0);
}
__device__ __forceinline__ void wr_vt(float2 va, float2 vb, f16* Ph, f16* Pl, int t) {
    const int n0 = (t >> 5) << 1, e0 = (t & 31) << 1;
    HL ax = split2(va.x), ay = split2(va.y), bx = split2(vb.x), by = split2(vb.y);
    const int o0 = swi(e0, n0), o1 = swi(e0 + 1, n0);
    *(f16x2*)(Ph + o0) = mk2(ax.h, bx.h);
    *(f16x2*)(Pl + o0) = mk2(ax.l, bx.l);
    *(f16x2*)(Ph + o1) = mk2(ay.h, by.h);
    *(f16x2*)(Pl + o1) = mk2(ay.l, by.l);
}
__device__ __forceinline__ void pool_global1024(const float* __restrict__ src,
                                                f16* Ph, f16* Pl, int t) {
    const int L = t >> 4, d0 = (t & 15) << 2;
    const int nb = ((L >> 3) << 5) + ((L & 7) << 1);
    const float* p = src + (size_t)nb * 64 + d0;
    float4 a = *(const float4*)p;
    float4 b = *(const float4*)(p + 64);
    float4 c = *(const float4*)(p + 1024);
    float4 d = *(const float4*)(p + 1088);
    HL s0 = split2(0.25f * (a.x + b.x + c.x + d.x));
    HL s1 = split2(0.25f * (a.y + b.y + c.y + d.y));
    HL s2 = split2(0.25f * (a.z + b.z + c.z + d.z));
    HL s3 = split2(0.25f * (a.w + b.w + c.w + d.w));
    const int o = swi(L, d0);
    *(f16x4*)(Ph + o) = mk4(s0.h, s1.h, s2.h, s3.h);
    *(f16x4*)(Pl + o) = mk4(s0.l, s1.l, s2.l, s3.l);
}
__device__ __forceinline__ void pool_lds512(const f16* Kh, const f16* Kl,
                                            f16* Ph, f16* Pl, int t, int tt) {
    const int ll = t >> 5, d0 = (t & 31) << 1;
    const int rb = ((ll >> 3) << 5) + ((ll & 7) << 1);
    float s0 = 0.f, s1 = 0.f;
#pragma unroll
    for (int rr = 0; rr < 4; ++rr) {
        const int r = rb + (rr & 1) + ((rr >> 1) << 4);
        const int o = swi(r, d0);
        f16x2 h = *(const f16x2*)(Kh + o);
        f16x2 l = *(const f16x2*)(Kl + o);
        s0 += join2(h[0], l[0]);
        s1 += join2(h[1], l[1]);
    }
    const int L = (tt << 4) + ll;
    HL p0 = split2(0.25f * s0), p1 = split2(0.25f * s1);
    const int o = swi(L, d0);
    *(f16x2*)(Ph + o) = mk2(p0.h, p1.h);
    *(f16x2*)(Pl + o) = mk2(p0.l, p1.l);
}

// ---- k_reduce helpers (unchanged) ----
__device__ __forceinline__ f32x16 mm64q(const f16* __restrict__ Ah, const f16* __restrict__ Al,
                                        const f16* __restrict__ Bh, const f16* __restrict__ Bl,
                                        int lane, int wr, int wc, f32x16 acc) {
    const int cl = lane & 31, hh = lane >> 5;
    const int ar = (wr << 5) + cl, br = (wc << 5) + cl;
    const int abase = ar << 6, axor = (ar & 7) << 3;
    const int bbase = br << 6, bxor = (br & 7) << 3;
    f32x16 ax1 = z16();
    f32x16 ax2 = z16();
#pragma unroll
    for (int ks = 0; ks < 4; ++ks) {
        const int k0 = (ks << 4) + (hh << 3);
        const int ao = abase + (k0 ^ axor);
        const int bo = bbase + (k0 ^ bxor);
        f16x8 a_h = *(const f16x8*)(Ah + ao);
        f16x8 a_l = *(const f16x8*)(Al + ao);
        f16x8 b_h = *(const f16x8*)(Bh + bo);
        f16x8 b_l = *(const f16x8*)(Bl + bo);
        acc = __builtin_amdgcn_mfma_f32_32x32x16_f16(a_h, b_h, acc, 0, 0, 0);
        ax1 = __builtin_amdgcn_mfma_f32_32x32x16_f16(a_h, b_l, ax1, 0, 0, 0);
        ax2 = __builtin_amdgcn_mfma_f32_32x32x16_f16(a_l, b_h, ax2, 0, 0, 0);
    }
    acc += (ax1 + ax2) * LINV;
    return acc;
}
__device__ __forceinline__ void pool_global_r(const float* __restrict__ src,
                                              f16* Ph, f16* Pl, int t) {
    const int ll = t >> 4, d0 = (t & 15) << 2;
    const int rb = ((ll >> 3) << 5) + ((ll & 7) << 1);
#pragma unroll
    for (int tt = 0; tt < 4; ++tt) {
        const float* p = src + (size_t)((tt << 6) + rb) * 64 + d0;
        float4 a = *(const float4*)p;
        float4 b = *(const float4*)(p + 64);
        float4 c = *(const float4*)(p + 1024);
        float4 d = *(const float4*)(p + 1088);
        const int L = (tt << 4) + ll;
        split_w(Ph, Pl, L, d0 + 0, 0.25f * (a.x + b.x + c.x + d.x));
        split_w(Ph, Pl, L, d0 + 1, 0.25f * (a.y + b.y + c.y + d.y));
        split_w(Ph, Pl, L, d0 + 2, 0.25f * (a.z + b.z + c.z + d.z));
        split_w(Ph, Pl, L, d0 + 3, 0.25f * (a.w + b.w + c.w + d.w));
    }
}

#define WAVE_SUM32(v)            \
    v += __shfl_xor(v, 1);       \
    v += __shfl_xor(v, 2);       \
    v += __shfl_xor(v, 4);       \
    v += __shfl_xor(v, 8);       \
    v += __shfl_xor(v, 16);

__global__ void k_init(float* ws) {
    if (threadIdx.x < 2) ws[threadIdx.x] = 0.0f;
}

__global__ __launch_bounds__(TPB_R) void k_reduce(const float* __restrict__ q,
                                                  const float* __restrict__ k,
                                                  float* __restrict__ ws) {
    __shared__ f16 pls[4 * 4096];
    __shared__ float rowS[64], colS[64];
    const int t = threadIdx.x, g = blockIdx.x;
    const int lane = t & 63, wv = t >> 6, wr = wv >> 1, wc = wv & 1;
    const int cl = lane & 31, hh = lane >> 5;
    if (t < 64) rowS[t] = 0.f;
    else if (t < 128) colS[t - 64] = 0.f;
    pool_global_r(q + (size_t)g * 16384, pls, pls + 4096, t);
    pool_global_r(k + (size_t)g * 16384, pls + 8192, pls + 12288, t);
    __syncthreads();
    f32x16 a = mm64q(pls, pls + 4096, pls + 8192, pls + 12288, lane, wr, wc, z16());
    float colp = 0.f;
#pragma unroll
    for (int m = 0; m < 16; ++m) {
        float x = activ_r(a[m]);
        const int R = (wr << 5) + (m & 3) + ((m >> 2) << 3) + (hh << 2);
        float vs = x;
        WAVE_SUM32(vs)
        if (cl == 0) atomicAdd(&rowS[R], vs);
        colp += x;
    }
    colp += __shfl_xor(colp, 32);
    if (hh == 0) atomicAdd(&colS[(wc << 5) + cl], colp);
    __syncthreads();
    if (t < 64) {
        float vmx = rowS[t];
        for (int off = 1; off < 64; off <<= 1) vmx = fmaxf(vmx, __shfl_xor(vmx, off));
        if (t == 0) atomicMax((int*)ws, __float_as_int(vmx));
    } else if (t < 128) {
        float vmx = colS[t - 64];
        for (int off = 1; off < 64; off <<= 1) vmx = fmaxf(vmx, __shfl_xor(vmx, off));
        if (t == 64) atomicMax(((int*)ws) + 1, __float_as_int(vmx));
    }
}

// ============================ k_main (v11) ============================
__global__ __launch_bounds__(TPB_M, 4) void k_main(const float* __restrict__ q,
                                                   const float* __restrict__ k,
                                                   const float* __restrict__ v,
                                                   const float* __restrict__ ws,
                                                   float* __restrict__ out) {
    extern __shared__ f16 smu[];
    float* kv1 = (float*)(smu + NPLANES * 4096);
    const int t = threadIdx.x, g = blockIdx.x;
    const int lane = t & 63, w = t >> 6;
    const int ti = w & 3, tj = w >> 2;
    const int fr = lane & 15, kg = lane >> 4;
    const int arow = (ti << 4) + fr;
    const int brow = (tj << 4) + fr;
    const int C = brow;
    const int Rb = (ti << 4) + (kg << 2);
    const float* Gq = q + (size_t)g * 16384;
    const float* Gk = k + (size_t)g * 16384;
    const float* Gv = v + (size_t)g * 16384;
    float* og = out + (size_t)g * 16384;

    f16* Xh  = smu +  0 * 4096; f16* Xl  = smu +  1 * 4096;
    f16* SAh = smu +  2 * 4096; f16* SAl = smu +  3 * 4096;
    f16* SBh = smu +  4 * 4096; f16* SBl = smu +  5 * 4096;
    f16* KMh = smu +  6 * 4096; f16* KMl = smu +  7 * 4096;
    f16* SCh = smu +  8 * 4096; f16* SCl = smu +  9 * 4096;
    f16* KVh = smu + 10 * 4096; f16* KVl = smu + 11 * 4096;
    f16* Z0rh= smu + 12 * 4096; f16* Z0rl= smu + 13 * 4096;
    f16* Z0th= smu + 14 * 4096; f16* Z0tl= smu + 15 * 4096;

    // ones B-frag for row-sum MFMAs
    Frag fOnes;
    {
        f16x8 one8, zer8;
#pragma unroll
        for (int i = 0; i < 8; ++i) { one8[i] = (f16)1.0f; zer8[i] = (f16)0.0f; }
        fOnes.h[0] = one8; fOnes.h[1] = one8;
        fOnes.l[0] = zer8; fOnes.l[1] = zer8;
    }

    // ---- prologue: pool QM -> Z0r planes; K0->SA, V0t->SB ----
    pool_global1024(Gq, Z0rh, Z0rl, t);
    {
        float4 kreg = *(const float4*)(Gk + (size_t)t * 4);
        float2 va, vb; ld_vt(Gv, t, va, vb);
        wr_rm(kreg, SAh, SAl, t);
        wr_vt(va, vb, SBh, SBl, t);
    }
    __syncthreads();

    Frag fQM = ld_frag(Z0rh, Z0rl, arow, kg);

    // ---- phase E: KV = activ(QM @ K^T) @ V ; pool KM ; kv1 via ones-MFMA ----
    f32x4 kva = z4();
    f32x4 kva1 = z4();
    for (int tt = 0; tt < 4; ++tt) {
        f16* vch = (tt & 1) ? Xh : SBh;  f16* vcl = (tt & 1) ? Xl : SBl;
        f16* vnh = (tt & 1) ? SBh : Xh;  f16* vnl = (tt & 1) ? SBl : Xl;
        float4 kregN; float2 vaN, vbN;
        if (tt < 3) {
            kregN = *(const float4*)(Gk + (size_t)(tt + 1) * 4096 + (size_t)t * 4);
            ld_vt(Gv + (size_t)(tt + 1) * 4096, t, vaN, vbN);
        }
        // e2: pool KM; S = activ(QM@K^T) -> SC; stage next V^T
        if (t < 512) pool_lds512(SAh, SAl, KMh, KMl, t, tt);
        {
            Frag bK = ld_frag(SAh, SAl, brow, kg);
            f32x4 s = mm16_rr(fQM, bK, z4());
            float sv[4];
#pragma unroll
            for (int m = 0; m < 4; ++m) sv[m] = activ_f(s[m]);
            wfrag_rm(SCh, SCl, Rb, C, sv);
        }
        if (tt < 3) wr_vt(vaN, vbN, vnh, vnl, t);
        __syncthreads();
        // e3: KV += S @ V ; kv1 += S @ ones ; stage next K
        {
            Frag aS = ld_frag(SCh, SCl, arow, kg);
            Frag bV = ld_frag(vch, vcl, brow, kg);
            kva  = mm16_rr(aS, bV, kva);
            kva1 = mm16_rr(aS, fOnes, kva1);
        }
        if (tt < 3) wr_rm(kregN, SAh, SAl, t);
        __syncthreads();
    }

    // ---- phase B: KV store (T-layout); X = activ(QM@KM^T); Z-init; kv1 write ----
    {
        float kvv[4] = {kva[0], kva[1], kva[2], kva[3]};
        wfrag_t(KVh, KVl, Rb, C, kvv);
        Frag fKMb = ld_frag(KMh, KMl, brow, kg);
        f32x4 x0 = mm16_rr(fQM, fKMb, z4());
        const float scale = ZS / (ws[0] * ws[1] + 1e-15f);
        float xv[4], zv[4];
#pragma unroll
        for (int m = 0; m < 4; ++m) { xv[m] = activ_f(x0[m]); zv[m] = xv[m] * scale; }
        wfrag_rm(Xh, Xl, Rb, C, xv);
        wfrag_t (Z0rh, Z0rl, Rb, C, zv);   // Z row-major
        wfrag_rm(Z0th, Z0tl, Rb, C, zv);   // Z^T (B-layout)
        if (tj == 0 && fr == 0) {
#pragma unroll
            for (int m = 0; m < 4; ++m) kv1[Rb + m] = kva1[m];
        }
    }
    __syncthreads();

    // ---- phase D: 6 Newton-Schulz iterations (unchanged from v5) ----
    Frag fX = ld_frag(Xh, Xl, arow, kg);
    f16 *zrh = Z0rh, *zrl = Z0rl, *zth = Z0th, *ztl = Z0tl;
    f16 *nrh = SAh,  *nrl = SAl,  *nth = SCh,  *ntl = SCl;
#pragma unroll
    for (int it = 0; it < 6; ++it) {
        Frag bz = ld_frag(zth, ztl, brow, kg);
        f32x4 a1 = mm16_rr(fX, bz, z4());
        float t1k[4];
#pragma unroll
        for (int m = 0; m < 4; ++m) t1k[m] = a1[m] * ZINV;
        wfrag_rm(nrh, nrl, Rb, C, t1k);
        wfrag_t (nth, ntl, Rb, C, t1k);
        __syncthreads();
        Frag aT1 = ld_frag(nrh, nrl, arow, kg);
        Frag bT1 = ld_frag(nth, ntl, brow, kg);
        f32x4 a2 = mm16_rr(aT1, bT1, z4());
        float t2k[4];
#pragma unroll
        for (int m = 0; m < 4; ++m) t2k[m] = a2[m];
        wfrag_rm(Xh, Xl, Rb, C, t2k);
        __syncthreads();
        Frag aT2 = ld_frag(Xh, Xl, arow, kg);
        f32x4 a3 = mm16_rr(aT2, bT1, z4());
        float ov[4];
#pragma unroll
        for (int m = 0; m < 4; ++m) {
            const int R = Rb + m;
            ov[m] = ((R == C) ? 13.f : 0.f) - 15.f * t1k[m] + 7.f * t2k[m] - a3[m];
        }
        wfrag_t(SBh, SBl, Rb, C, ov);
        __syncthreads();
        Frag aZ = ld_frag(zrh, zrl, arow, kg);
        Frag bO = ld_frag(SBh, SBl, brow, kg);
        f32x4 a4 = mm16_rr(aZ, bO, z4());
        float zk[4];
#pragma unroll
        for (int m = 0; m < 4; ++m) zk[m] = 0.25f * a4[m];
        wfrag_rm(nrh, nrl, Rb, C, zk);
        wfrag_t (nth, ntl, Rb, C, zk);
        __syncthreads();
        f16* tp;
        tp = zrh; zrh = nrh; nrh = tp;  tp = zrl; zrl = nrl; nrl = tp;
        tp = zth; zth = nth; nth = tp;  tp = ztl; ztl = ntl; ntl = tp;
    }
    // final Z: Zr=Z0r, Zt=Z0t

    // ---- phase F: out = (activ(q@KM^T) @ Z @ KV) / den ----
    Frag fKM = ld_frag(KMh, KMl, brow, kg);
    Frag fZt = ld_frag(Z0th, Z0tl, brow, kg);
    Frag fKV = ld_frag(KVh, KVl, brow, kg);
    // split-f16 B-frag of kv1 (den = w @ kv1 via MFMA)
    Frag fKv1;
#pragma unroll
    for (int s = 0; s < 2; ++s) {
        const float* kp = kv1 + (s << 5) + (kg << 3);
        float4 A = *(const float4*)kp;
        float4 B = *(const float4*)(kp + 4);
        HL s0 = split2(A.x), s1 = split2(A.y), s2 = split2(A.z), s3 = split2(A.w);
        HL s4 = split2(B.x), s5 = split2(B.y), s6 = split2(B.z), s7 = split2(B.w);
        f16x8 h, l;
        h[0]=s0.h; h[1]=s1.h; h[2]=s2.h; h[3]=s3.h; h[4]=s4.h; h[5]=s5.h; h[6]=s6.h; h[7]=s7.h;
        l[0]=s0.l; l[1]=s1.l; l[2]=s2.l; l[3]=s3.l; l[4]=s4.l; l[5]=s5.l; l[6]=s6.l; l[7]=s7.l;
        fKv1.h[s] = h; fKv1.l[s] = l;
    }
    // prefetched q rows (this lane's A-frag source floats)
    float4 qp0, qp1, qp2, qp3;
#define LOAD_Q(tt_)                                                              \
    {                                                                            \
        const float* rp = Gq + (size_t)(((tt_) << 6) + arow) * 64 + (kg << 3);   \
        qp0 = *(const float4*)(rp);      qp1 = *(const float4*)(rp + 4);         \
        qp2 = *(const float4*)(rp + 32); qp3 = *(const float4*)(rp + 36);        \
    }
    LOAD_Q(0)
    for (int tt = 0; tt < 4; ++tt) {
        // fA: qk = activ(q @ KM^T) -> SC   (q A-frag from registers)
        {
            Frag aQ;
            {
                HL s0 = split2(qp0.x), s1 = split2(qp0.y), s2 = split2(qp0.z), s3 = split2(qp0.w);
                HL s4 = split2(qp1.x), s5 = split2(qp1.y), s6 = split2(qp1.z), s7 = split2(qp1.w);
                f16x8 h, l;
                h[0]=s0.h; h[1]=s1.h; h[2]=s2.h; h[3]=s3.h; h[4]=s4.h; h[5]=s5.h; h[6]=s6.h; h[7]=s7.h;
                l[0]=s0.l; l[1]=s1.l; l[2]=s2.l; l[3]=s3.l; l[4]=s4.l; l[5]=s5.l; l[6]=s6.l; l[7]=s7.l;
                aQ.h[0] = h; aQ.l[0] = l;
                HL t0 = split2(qp2.x), t1 = split2(qp2.y), t2 = split2(qp2.z), t3 = split2(qp2.w);
                HL t4 = split2(qp3.x), t5 = split2(qp3.y), t6 = split2(qp3.z), t7 = split2(qp3.w);
                f16x8 h2, l2;
                h2[0]=t0.h; h2[1]=t1.h; h2[2]=t2.h; h2[3]=t3.h; h2[4]=t4.h; h2[5]=t5.h; h2[6]=t6.h; h2[7]=t7.h;
                l2[0]=t0.l; l2[1]=t1.l; l2[2]=t2.l; l2[3]=t3.l; l2[4]=t4.l; l2[5]=t5.l; l2[6]=t6.l; l2[7]=t7.l;
                aQ.h[1] = h2; aQ.l[1] = l2;
            }
            f32x4 q0 = mm16_rr(aQ, fKM, z4());
            float qv[4];
#pragma unroll
            for (int m = 0; m < 4; ++m) qv[m] = activ_f(q0[m]);
            wfrag_rm(SCh, SCl, Rb, C, qv);
        }
        __syncthreads();
        // fB: w = qk @ Z -> SB ; prefetch next q
        {
            Frag aK = ld_frag(SCh, SCl, arow, kg);
            f32x4 w0 = mm16_rr(aK, fZt, z4());
            float wv[4];
#pragma unroll
            for (int m = 0; m < 4; ++m) wv[m] = w0[m] * ZINV;
            wfrag_rm(SBh, SBl, Rb, C, wv);
        }
        if (tt < 3) LOAD_Q(tt + 1)
        __syncthreads();
        // fC: prod = w @ KV ; den = w @ kv1 (MFMA) ; divide ; store
        {
            Frag aW = ld_frag(SBh, SBl, arow, kg);
            f32x4 p0 = mm16_rr(aW, fKV, z4());
            f32x4 d4 = mm16_rr(aW, fKv1, z4());
#pragma unroll
            for (int m = 0; m < 4; ++m) {
                const int R = Rb + m;
                const float inv = 1.0f / (d4[m] + 1e-12f);
                og[(size_t)((tt << 6) + R) * 64 + C] = p0[m] * inv;
            }
        }
        __syncthreads();
    }
#undef LOAD_Q
}

extern "C" void kernel_launch(void* const* d_in, const int* in_sizes, int n_in,
                              void* d_out, int out_size, void* d_ws, size_t ws_size,
                              hipStream_t stream) {
    const float* q = (const float*)d_in[0];
    const float* k = (const float*)d_in[1];
    const float* v = (const float*)d_in[2];
    float* out = (float*)d_out;
    float* ws  = (float*)d_ws;
    (void)in_sizes; (void)n_in; (void)out_size; (void)ws_size;

    hipFuncSetAttribute((const void*)k_main,
                        hipFuncAttributeMaxDynamicSharedMemorySize, SMEM_BYTES);

    k_init<<<1, 64, 0, stream>>>(ws);
    k_reduce<<<G_TOT, TPB_R, 0, stream>>>(q, k, ws);
    k_main<<<G_TOT, TPB_M, SMEM_BYTES, stream>>>(q, k, v, ws, out);
}

// Round 13
// 758.746 us; speedup vs baseline: 1.4617x; 1.0468x over previous
//
#include <hip/hip_runtime.h>
#include <math.h>

// PnPNystra attention, MFMA v12 = v11 + barrier-graph restructure:
//  - Newton-Schulz in Horner-parallel form: 3 barriers/iter (was 4):
//      ph1 M=X@Z ; ph2 {P=M@M, W=Z@M} ; ph3 Y=W@(7M-P), Znew=0.25(13Z-15W+Y)
//    (in-place Z update, no identity-matmul, 12-MFMA middle phase)
//  - Phase F software-pipelined across the 4 independent q-tiles:
//      prod(t) || w(t+1) || qk(t+2), 6 barriers (was 12)
//  - kv1 kept as split-f16 LDS; all F B-frags loaded per phase (VGPR<=128)
// Numerics: split f16 (v ~= h + l/2048), 3x mfma_f32_16x16x32_f16, Z scaled 1024.
// G=4096 groups, N=256, d=64, L=64. 1024 thr / 16 waves, 16 LDS planes.

#define G_TOT 4096
#define TPB_R 256
#define TPB_M 1024
typedef _Float16 f16;
typedef __attribute__((ext_vector_type(2))) _Float16 f16x2;
typedef __attribute__((ext_vector_type(4))) _Float16 f16x4;
typedef __attribute__((ext_vector_type(8))) _Float16 f16x8;
typedef __attribute__((ext_vector_type(4))) float f32x4;
typedef __attribute__((ext_vector_type(16))) float f32x16;

#define NPLANES 16
#define SMEM_BYTES (NPLANES * 4096 * 2 + 256)  // + kv1 split (2x64 f16)

#define LSCALE 2048.0f
#define LINV   (1.0f / 2048.0f)
#define ZS     1024.0f
#define ZINV   (1.0f / 1024.0f)

struct HL { f16 h, l; };
__device__ __forceinline__ HL split2(float v) {
    HL r;
    r.h = (f16)v;
    r.l = (f16)((v - (float)r.h) * LSCALE);
    return r;
}
__device__ __forceinline__ float join2(f16 h, f16 l) {
    return (float)h + (float)l * LINV;
}
__device__ __forceinline__ int swi(int r, int c) {
    return (r << 6) + (c ^ ((r & 7) << 3));
}
__device__ __forceinline__ float activ_f(float x) {
    return __expf(fminf(x, 5.0f)) + fmaxf(x - 5.0f, 0.0f);
}
__device__ __forceinline__ float activ_r(float x) {
    return expf(fminf(x, 5.0f)) + fmaxf(x - 5.0f, 0.0f);
}
__device__ __forceinline__ void split_w(f16* Ph, f16* Pl, int r, int c, float v) {
    HL s = split2(v);
    const int o = swi(r, c);
    Ph[o] = s.h;
    Pl[o] = s.l;
}
__device__ __forceinline__ f16x2 mk2(f16 a, f16 b) { f16x2 r; r[0]=a; r[1]=b; return r; }
__device__ __forceinline__ f16x4 mk4(f16 a, f16 b, f16 c, f16 d) { f16x4 r; r[0]=a;r[1]=b;r[2]=c;r[3]=d; return r; }
__device__ __forceinline__ f32x4 z4() { f32x4 z = {0.f,0.f,0.f,0.f}; return z; }
__device__ __forceinline__ f32x16 z16() {
    f32x16 z;
#pragma unroll
    for (int i = 0; i < 16; ++i) z[i] = 0.f;
    return z;
}

struct Frag { f16x8 h[2], l[2]; };

__device__ __forceinline__ Frag ld_frag(const f16* __restrict__ Ph,
                                        const f16* __restrict__ Pl,
                                        int row, int kg) {
    Frag f;
    const int base = row << 6, x = (row & 7) << 3;
#pragma unroll
    for (int s = 0; s < 2; ++s) {
        const int o = base + ((((s << 5) + (kg << 3))) ^ x);
        f.h[s] = *(const f16x8*)(Ph + o);
        f.l[s] = *(const f16x8*)(Pl + o);
    }
    return f;
}

// 3-term split matmul, 2 accumulator chains
__device__ __forceinline__ f32x4 mm16_rr(const Frag& A, const Frag& B, f32x4 acc) {
    f32x4 ax = z4();
#pragma unroll
    for (int s = 0; s < 2; ++s) {
        acc = __builtin_amdgcn_mfma_f32_16x16x32_f16(A.h[s], B.h[s], acc, 0, 0, 0);
        ax  = __builtin_amdgcn_mfma_f32_16x16x32_f16(A.h[s], B.l[s], ax, 0, 0, 0);
        ax  = __builtin_amdgcn_mfma_f32_16x16x32_f16(A.l[s], B.h[s], ax, 0, 0, 0);
    }
    acc += ax * LINV;
    return acc;
}

__device__ __forceinline__ void wfrag_rm(f16* Ph, f16* Pl, int Rb, int C, const float* v) {
#pragma unroll
    for (int m = 0; m < 4; ++m) split_w(Ph, Pl, Rb + m, C, v[m]);
}
__device__ __forceinline__ void wfrag_t(f16* Ph, f16* Pl, int Rb, int C, const float* v) {
    const int o = swi(C, Rb);
    HL s0 = split2(v[0]), s1 = split2(v[1]), s2 = split2(v[2]), s3 = split2(v[3]);
    *(f16x4*)(Ph + o) = mk4(s0.h, s1.h, s2.h, s3.h);
    *(f16x4*)(Pl + o) = mk4(s0.l, s1.l, s2.l, s3.l);
}

// ---- staging helpers (1024 threads) ----
__device__ __forceinline__ void wr_rm(float4 vv, f16* Ph, f16* Pl, int t) {
    const int r = t >> 4, c4 = (t & 15) << 2;
    const int o = swi(r, c4);
    HL s0 = split2(vv.x), s1 = split2(vv.y), s2 = split2(vv.z), s3 = split2(vv.w);
    *(f16x4*)(Ph + o) = mk4(s0.h, s1.h, s2.h, s3.h);
    *(f16x4*)(Pl + o) = mk4(s0.l, s1.l, s2.l, s3.l);
}
__device__ __forceinline__ void ld_vt(const float* __restrict__ src, int t,
                                      float2& va, float2& vb) {
    const int n0 = (t >> 5) << 1, e0 = (t & 31) << 1;
    va = *(const float2*)(src + (size_t)n0 * 64 + e0);
    vb = *(const float2*)(src + (size_t)(n0 + 1) * 64 + e0);
}
__device__ __forceinline__ void wr_vt(float2 va, float2 vb, f16* Ph, f16* Pl, int t) {
    const int n0 = (t >> 5) << 1, e0 = (t & 31) << 1;
    HL ax = split2(va.x), ay = split2(va.y), bx = split2(vb.x), by = split2(vb.y);
    const int o0 = swi(e0, n0), o1 = swi(e0 + 1, n0);
    *(f16x2*)(Ph + o0) = mk2(ax.h, bx.h);
    *(f16x2*)(Pl + o0) = mk2(ax.l, bx.l);
    *(f16x2*)(Ph + o1) = mk2(ay.h, by.h);
    *(f16x2*)(Pl + o1) = mk2(ay.l, by.l);
}
__device__ __forceinline__ void pool_global1024(const float* __restrict__ src,
                                                f16* Ph, f16* Pl, int t) {
    const int L = t >> 4, d0 = (t & 15) << 2;
    const int nb = ((L >> 3) << 5) + ((L & 7) << 1);
    const float* p = src + (size_t)nb * 64 + d0;
    float4 a = *(const float4*)p;
    float4 b = *(const float4*)(p + 64);
    float4 c = *(const float4*)(p + 1024);
    float4 d = *(const float4*)(p + 1088);
    HL s0 = split2(0.25f * (a.x + b.x + c.x + d.x));
    HL s1 = split2(0.25f * (a.y + b.y + c.y + d.y));
    HL s2 = split2(0.25f * (a.z + b.z + c.z + d.z));
    HL s3 = split2(0.25f * (a.w + b.w + c.w + d.w));
    const int o = swi(L, d0);
    *(f16x4*)(Ph + o) = mk4(s0.h, s1.h, s2.h, s3.h);
    *(f16x4*)(Pl + o) = mk4(s0.l, s1.l, s2.l, s3.l);
}
__device__ __forceinline__ void pool_lds512(const f16* Kh, const f16* Kl,
                                            f16* Ph, f16* Pl, int t, int tt) {
    const int ll = t >> 5, d0 = (t & 31) << 1;
    const int rb = ((ll >> 3) << 5) + ((ll & 7) << 1);
    float s0 = 0.f, s1 = 0.f;
#pragma unroll
    for (int rr = 0; rr < 4; ++rr) {
        const int r = rb + (rr & 1) + ((rr >> 1) << 4);
        const int o = swi(r, d0);
        f16x2 h = *(const f16x2*)(Kh + o);
        f16x2 l = *(const f16x2*)(Kl + o);
        s0 += join2(h[0], l[0]);
        s1 += join2(h[1], l[1]);
    }
    const int L = (tt << 4) + ll;
    HL p0 = split2(0.25f * s0), p1 = split2(0.25f * s1);
    const int o = swi(L, d0);
    *(f16x2*)(Ph + o) = mk2(p0.h, p1.h);
    *(f16x2*)(Pl + o) = mk2(p0.l, p1.l);
}

// ---- k_reduce helpers (unchanged) ----
__device__ __forceinline__ f32x16 mm64q(const f16* __restrict__ Ah, const f16* __restrict__ Al,
                                        const f16* __restrict__ Bh, const f16* __restrict__ Bl,
                                        int lane, int wr, int wc, f32x16 acc) {
    const int cl = lane & 31, hh = lane >> 5;
    const int ar = (wr << 5) + cl, br = (wc << 5) + cl;
    const int abase = ar << 6, axor = (ar & 7) << 3;
    const int bbase = br << 6, bxor = (br & 7) << 3;
    f32x16 ax1 = z16();
    f32x16 ax2 = z16();
#pragma unroll
    for (int ks = 0; ks < 4; ++ks) {
        const int k0 = (ks << 4) + (hh << 3);
        const int ao = abase + (k0 ^ axor);
        const int bo = bbase + (k0 ^ bxor);
        f16x8 a_h = *(const f16x8*)(Ah + ao);
        f16x8 a_l = *(const f16x8*)(Al + ao);
        f16x8 b_h = *(const f16x8*)(Bh + bo);
        f16x8 b_l = *(const f16x8*)(Bl + bo);
        acc = __builtin_amdgcn_mfma_f32_32x32x16_f16(a_h, b_h, acc, 0, 0, 0);
        ax1 = __builtin_amdgcn_mfma_f32_32x32x16_f16(a_h, b_l, ax1, 0, 0, 0);
        ax2 = __builtin_amdgcn_mfma_f32_32x32x16_f16(a_l, b_h, ax2, 0, 0, 0);
    }
    acc += (ax1 + ax2) * LINV;
    return acc;
}
__device__ __forceinline__ void pool_global_r(const float* __restrict__ src,
                                              f16* Ph, f16* Pl, int t) {
    const int ll = t >> 4, d0 = (t & 15) << 2;
    const int rb = ((ll >> 3) << 5) + ((ll & 7) << 1);
#pragma unroll
    for (int tt = 0; tt < 4; ++tt) {
        const float* p = src + (size_t)((tt << 6) + rb) * 64 + d0;
        float4 a = *(const float4*)p;
        float4 b = *(const float4*)(p + 64);
        float4 c = *(const float4*)(p + 1024);
        float4 d = *(const float4*)(p + 1088);
        const int L = (tt << 4) + ll;
        split_w(Ph, Pl, L, d0 + 0, 0.25f * (a.x + b.x + c.x + d.x));
        split_w(Ph, Pl, L, d0 + 1, 0.25f * (a.y + b.y + c.y + d.y));
        split_w(Ph, Pl, L, d0 + 2, 0.25f * (a.z + b.z + c.z + d.z));
        split_w(Ph, Pl, L, d0 + 3, 0.25f * (a.w + b.w + c.w + d.w));
    }
}

#define WAVE_SUM32(v)            \
    v += __shfl_xor(v, 1);       \
    v += __shfl_xor(v, 2);       \
    v += __shfl_xor(v, 4);       \
    v += __shfl_xor(v, 8);       \
    v += __shfl_xor(v, 16);

__global__ void k_init(float* ws) {
    if (threadIdx.x < 2) ws[threadIdx.x] = 0.0f;
}

__global__ __launch_bounds__(TPB_R) void k_reduce(const float* __restrict__ q,
                                                  const float* __restrict__ k,
                                                  float* __restrict__ ws) {
    __shared__ f16 pls[4 * 4096];
    __shared__ float rowS[64], colS[64];
    const int t = threadIdx.x, g = blockIdx.x;
    const int lane = t & 63, wv = t >> 6, wr = wv >> 1, wc = wv & 1;
    const int cl = lane & 31, hh = lane >> 5;
    if (t < 64) rowS[t] = 0.f;
    else if (t < 128) colS[t - 64] = 0.f;
    pool_global_r(q + (size_t)g * 16384, pls, pls + 4096, t);
    pool_global_r(k + (size_t)g * 16384, pls + 8192, pls + 12288, t);
    __syncthreads();
    f32x16 a = mm64q(pls, pls + 4096, pls + 8192, pls + 12288, lane, wr, wc, z16());
    float colp = 0.f;
#pragma unroll
    for (int m = 0; m < 16; ++m) {
        float x = activ_r(a[m]);
        const int R = (wr << 5) + (m & 3) + ((m >> 2) << 3) + (hh << 2);
        float vs = x;
        WAVE_SUM32(vs)
        if (cl == 0) atomicAdd(&rowS[R], vs);
        colp += x;
    }
    colp += __shfl_xor(colp, 32);
    if (hh == 0) atomicAdd(&colS[(wc << 5) + cl], colp);
    __syncthreads();
    if (t < 64) {
        float vmx = rowS[t];
        for (int off = 1; off < 64; off <<= 1) vmx = fmaxf(vmx, __shfl_xor(vmx, off));
        if (t == 0) atomicMax((int*)ws, __float_as_int(vmx));
    } else if (t < 128) {
        float vmx = colS[t - 64];
        for (int off = 1; off < 64; off <<= 1) vmx = fmaxf(vmx, __shfl_xor(vmx, off));
        if (t == 64) atomicMax(((int*)ws) + 1, __float_as_int(vmx));
    }
}

// ============================ k_main (v12) ============================
__global__ __launch_bounds__(TPB_M, 4) void k_main(const float* __restrict__ q,
                                                   const float* __restrict__ k,
                                                   const float* __restrict__ v,
                                                   const float* __restrict__ ws,
                                                   float* __restrict__ out) {
    extern __shared__ f16 smu[];
    f16* kv1h = smu + NPLANES * 4096;      // 64 f16
    f16* kv1l = kv1h + 64;                 // 64 f16
    const int t = threadIdx.x, g = blockIdx.x;
    const int lane = t & 63, w = t >> 6;
    const int ti = w & 3, tj = w >> 2;
    const int fr = lane & 15, kg = lane >> 4;
    const int arow = (ti << 4) + fr;
    const int brow = (tj << 4) + fr;
    const int C = brow;
    const int Rb = (ti << 4) + (kg << 2);
    const float* Gq = q + (size_t)g * 16384;
    const float* Gk = k + (size_t)g * 16384;
    const float* Gv = v + (size_t)g * 16384;
    float* og = out + (size_t)g * 16384;

    f16* Xh  = smu +  0 * 4096; f16* Xl  = smu +  1 * 4096;
    f16* SAh = smu +  2 * 4096; f16* SAl = smu +  3 * 4096;
    f16* SBh = smu +  4 * 4096; f16* SBl = smu +  5 * 4096;
    f16* KMh = smu +  6 * 4096; f16* KMl = smu +  7 * 4096;
    f16* SCh = smu +  8 * 4096; f16* SCl = smu +  9 * 4096;
    f16* KVh = smu + 10 * 4096; f16* KVl = smu + 11 * 4096;
    f16* Z0rh= smu + 12 * 4096; f16* Z0rl= smu + 13 * 4096;  // Zs row-major
    f16* Z0th= smu + 14 * 4096; f16* Z0tl= smu + 15 * 4096;  // Zs^T row-major

    // ones B-frag for kv1 row-sum MFMA
    Frag fOnes;
    {
        f16x8 one8, zer8;
#pragma unroll
        for (int i = 0; i < 8; ++i) { one8[i] = (f16)1.0f; zer8[i] = (f16)0.0f; }
        fOnes.h[0] = one8; fOnes.h[1] = one8;
        fOnes.l[0] = zer8; fOnes.l[1] = zer8;
    }

    // ---- prologue: pool QM -> Z0r planes; K0->SA, V0t->SB ----
    pool_global1024(Gq, Z0rh, Z0rl, t);
    {
        float4 kreg = *(const float4*)(Gk + (size_t)t * 4);
        float2 va, vb; ld_vt(Gv, t, va, vb);
        wr_rm(kreg, SAh, SAl, t);
        wr_vt(va, vb, SBh, SBl, t);
    }
    __syncthreads();

    Frag fQM = ld_frag(Z0rh, Z0rl, arow, kg);

    // ---- phase E: KV = activ(QM @ K^T) @ V ; pool KM ; kv1 via ones-MFMA ----
    f32x4 kva = z4();
    f32x4 kva1 = z4();
    for (int tt = 0; tt < 4; ++tt) {
        f16* vch = (tt & 1) ? Xh : SBh;  f16* vcl = (tt & 1) ? Xl : SBl;
        f16* vnh = (tt & 1) ? SBh : Xh;  f16* vnl = (tt & 1) ? SBl : Xl;
        float4 kregN; float2 vaN, vbN;
        if (tt < 3) {
            kregN = *(const float4*)(Gk + (size_t)(tt + 1) * 4096 + (size_t)t * 4);
            ld_vt(Gv + (size_t)(tt + 1) * 4096, t, vaN, vbN);
        }
        if (t < 512) pool_lds512(SAh, SAl, KMh, KMl, t, tt);
        {
            Frag bK = ld_frag(SAh, SAl, brow, kg);
            f32x4 s = mm16_rr(fQM, bK, z4());
            float sv[4];
#pragma unroll
            for (int m = 0; m < 4; ++m) sv[m] = activ_f(s[m]);
            wfrag_rm(SCh, SCl, Rb, C, sv);
        }
        if (tt < 3) wr_vt(vaN, vbN, vnh, vnl, t);
        __syncthreads();
        {
            Frag aS = ld_frag(SCh, SCl, arow, kg);
            Frag bV = ld_frag(vch, vcl, brow, kg);
            kva  = mm16_rr(aS, bV, kva);
            kva1 = mm16_rr(aS, fOnes, kva1);
        }
        if (tt < 3) wr_rm(kregN, SAh, SAl, t);
        __syncthreads();
    }

    // ---- phase B: KV store (T-layout); X = activ(QM@KM^T); Zs-init; kv1 split ----
    {
        float kvv[4] = {kva[0], kva[1], kva[2], kva[3]};
        wfrag_t(KVh, KVl, Rb, C, kvv);
        Frag fKMb = ld_frag(KMh, KMl, brow, kg);
        f32x4 x0 = mm16_rr(fQM, fKMb, z4());
        const float scale = ZS / (ws[0] * ws[1] + 1e-15f);
        float xv[4], zv[4];
#pragma unroll
        for (int m = 0; m < 4; ++m) { xv[m] = activ_f(x0[m]); zv[m] = xv[m] * scale; }
        wfrag_rm(Xh, Xl, Rb, C, xv);       // X rm
        wfrag_t (Z0rh, Z0rl, Rb, C, zv);   // Zs rm
        wfrag_rm(Z0th, Z0tl, Rb, C, zv);   // Zs^T rm
        if (tj == 0 && fr == 0) {
#pragma unroll
            for (int m = 0; m < 4; ++m) {
                HL s = split2(kva1[m]);
                kv1h[Rb + m] = s.h;
                kv1l[Rb + m] = s.l;
            }
        }
    }
    __syncthreads();

    // ---- phase D: 6 Newton-Schulz iterations, Horner-parallel, 3 barriers/iter ----
    // ph1: M = X@Z (unscaled) -> SA(rm), SC(^T)
    // ph2: P=M@M, Ws=Zs@M ; (7M-P)^T -> X ; Ws rm -> SB
    // ph3: Ys=Ws@(7M-P) ; Znew_s = 0.25(13 Zs - 15 Ws + Ys), in-place Z0r/Z0t
    Frag fX = ld_frag(Xh, Xl, arow, kg);
#pragma unroll
    for (int it = 0; it < 6; ++it) {
        Frag bz = ld_frag(Z0th, Z0tl, brow, kg);
        f32x4 a1 = mm16_rr(fX, bz, z4());
        float t1k[4];
#pragma unroll
        for (int m = 0; m < 4; ++m) t1k[m] = a1[m] * ZINV;
        wfrag_rm(SAh, SAl, Rb, C, t1k);
        wfrag_t (SCh, SCl, Rb, C, t1k);
        __syncthreads();
        Frag aM  = ld_frag(SAh, SAl, arow, kg);
        Frag bMt = ld_frag(SCh, SCl, brow, kg);
        f32x4 pP = mm16_rr(aM, bMt, z4());
        Frag aZ  = ld_frag(Z0rh, Z0rl, arow, kg);
        f32x4 wS = mm16_rr(aZ, bMt, z4());
        float opv[4], wv[4];
#pragma unroll
        for (int m = 0; m < 4; ++m) { opv[m] = 7.f * t1k[m] - pP[m]; wv[m] = wS[m]; }
        wfrag_t (Xh, Xl, Rb, C, opv);
        wfrag_rm(SBh, SBl, Rb, C, wv);
        __syncthreads();
        Frag aW  = ld_frag(SBh, SBl, arow, kg);
        Frag bOP = ld_frag(Xh, Xl, brow, kg);
        f32x4 yS = mm16_rr(aW, bOP, z4());
        float zk[4];
#pragma unroll
        for (int m = 0; m < 4; ++m) {
            const int o = swi(Rb + m, C);
            const float zs = join2(Z0rh[o], Z0rl[o]);
            zk[m] = 0.25f * (13.f * zs - 15.f * wv[m] + yS[m]);
        }
        wfrag_rm(Z0rh, Z0rl, Rb, C, zk);
        wfrag_t (Z0th, Z0tl, Rb, C, zk);
        __syncthreads();
    }
    // final: Zs rm in Z0r, Zs^T in Z0t

    // ---- phase F: pipelined — prod(t) || w(t+1) || qk(t+2), 6 barriers ----
    float4 qp0, qp1, qp2, qp3;
#define LOAD_Q(tt_)                                                              \
    {                                                                            \
        const float* rp = Gq + (size_t)(((tt_) << 6) + arow) * 64 + (kg << 3);   \
        qp0 = *(const float4*)(rp);      qp1 = *(const float4*)(rp + 4);         \
        qp2 = *(const float4*)(rp + 32); qp3 = *(const float4*)(rp + 36);        \
    }
#define BUILD_AQ(aQ_)                                                                          \
    {                                                                                          \
        HL s0 = split2(qp0.x), s1 = split2(qp0.y), s2 = split2(qp0.z), s3 = split2(qp0.w);     \
        HL s4 = split2(qp1.x), s5 = split2(qp1.y), s6 = split2(qp1.z), s7 = split2(qp1.w);     \
        f16x8 h, l;                                                                            \
        h[0]=s0.h; h[1]=s1.h; h[2]=s2.h; h[3]=s3.h; h[4]=s4.h; h[5]=s5.h; h[6]=s6.h; h[7]=s7.h;\
        l[0]=s0.l; l[1]=s1.l; l[2]=s2.l; l[3]=s3.l; l[4]=s4.l; l[5]=s5.l; l[6]=s6.l; l[7]=s7.l;\
        aQ_.h[0] = h; aQ_.l[0] = l;                                                            \
        HL t0 = split2(qp2.x), t1 = split2(qp2.y), t2 = split2(qp2.z), t3 = split2(qp2.w);     \
        HL t4 = split2(qp3.x), t5 = split2(qp3.y), t6 = split2(qp3.z), t7 = split2(qp3.w);     \
        f16x8 h2, l2;                                                                          \
        h2[0]=t0.h; h2[1]=t1.h; h2[2]=t2.h; h2[3]=t3.h; h2[4]=t4.h; h2[5]=t5.h; h2[6]=t6.h; h2[7]=t7.h; \
        l2[0]=t0.l; l2[1]=t1.l; l2[2]=t2.l; l2[3]=t3.l; l2[4]=t4.l; l2[5]=t5.l; l2[6]=t6.l; l2[7]=t7.l; \
        aQ_.h[1] = h2; aQ_.l[1] = l2;                                                          \
    }
    // qk(tt): aQ @ KM -> dst ; w(tt): ld(src) @ Z0t * ZINV -> dst ; prod(tt): ld(src) @ {KV, kv1} -> out
#define DO_QK(dsth, dstl)                                             \
    {                                                                 \
        Frag aQ; BUILD_AQ(aQ)                                         \
        Frag bKM = ld_frag(KMh, KMl, brow, kg);                       \
        f32x4 q0 = mm16_rr(aQ, bKM, z4());                            \
        float qv[4];                                                  \
        _Pragma("unroll")                                             \
        for (int m = 0; m < 4; ++m) qv[m] = activ_f(q0[m]);           \
        wfrag_rm(dsth, dstl, Rb, C, qv);                              \
    }
#define DO_W(srch, srcl, dsth, dstl)                                  \
    {                                                                 \
        Frag aK = ld_frag(srch, srcl, arow, kg);                      \
        Frag bZt = ld_frag(Z0th, Z0tl, brow, kg);                     \
        f32x4 w0 = mm16_rr(aK, bZt, z4());                            \
        float wv2[4];                                                 \
        _Pragma("unroll")                                             \
        for (int m = 0; m < 4; ++m) wv2[m] = w0[m] * ZINV;            \
        wfrag_rm(dsth, dstl, Rb, C, wv2);                             \
    }
#define DO_PROD(srch, srcl, tt_)                                      \
    {                                                                 \
        Frag aW2 = ld_frag(srch, srcl, arow, kg);                     \
        Frag bKV = ld_frag(KVh, KVl, brow, kg);                       \
        f32x4 p0 = mm16_rr(aW2, bKV, z4());                           \
        Frag fk;                                                      \
        _Pragma("unroll")                                             \
        for (int s = 0; s < 2; ++s) {                                 \
            const int o = (s << 5) + (kg << 3);                       \
            fk.h[s] = *(const f16x8*)(kv1h + o);                      \
            fk.l[s] = *(const f16x8*)(kv1l + o);                      \
        }                                                             \
        f32x4 d4 = mm16_rr(aW2, fk, z4());                            \
        _Pragma("unroll")                                             \
        for (int m = 0; m < 4; ++m) {                                 \
            const int R = Rb + m;                                     \
            og[(size_t)(((tt_) << 6) + R) * 64 + C] = p0[m] / (d4[m] + 1e-12f); \
        }                                                             \
    }

    LOAD_Q(0)
    // ph0: qk(0)->SC
    DO_QK(SCh, SCl)
    LOAD_Q(1)
    __syncthreads();
    // ph1: w(0):SC->SB ; qk(1)->SA
    DO_W(SCh, SCl, SBh, SBl)
    DO_QK(SAh, SAl)
    LOAD_Q(2)
    __syncthreads();
    // ph2: prod(0):SB ; w(1):SA->X ; qk(2)->SC
    DO_PROD(SBh, SBl, 0)
    DO_W(SAh, SAl, Xh, Xl)
    DO_QK(SCh, SCl)
    LOAD_Q(3)
    __syncthreads();
    // ph3: prod(1):X ; w(2):SC->SB ; qk(3)->SA
    DO_PROD(Xh, Xl, 1)
    DO_W(SCh, SCl, SBh, SBl)
    DO_QK(SAh, SAl)
    __syncthreads();
    // ph4: prod(2):SB ; w(3):SA->X
    DO_PROD(SBh, SBl, 2)
    DO_W(SAh, SAl, Xh, Xl)
    __syncthreads();
    // ph5: prod(3):X
    DO_PROD(Xh, Xl, 3)
#undef LOAD_Q
#undef BUILD_AQ
#undef DO_QK
#undef DO_W
#undef DO_PROD
}

extern "C" void kernel_launch(void* const* d_in, const int* in_sizes, int n_in,
                              void* d_out, int out_size, void* d_ws, size_t ws_size,
                              hipStream_t stream) {
    const float* q = (const float*)d_in[0];
    const float* k = (const float*)d_in[1];
    const float* v = (const float*)d_in[2];
    float* out = (float*)d_out;
    float* ws  = (float*)d_ws;
    (void)in_sizes; (void)n_in; (void)out_size; (void)ws_size;

    hipFuncSetAttribute((const void*)k_main,
                        hipFuncAttributeMaxDynamicSharedMemorySize, SMEM_BYTES);

    k_init<<<1, 64, 0, stream>>>(ws);
    k_reduce<<<G_TOT, TPB_R, 0, stream>>>(q, k, ws);
    k_main<<<G_TOT, TPB_M, SMEM_BYTES, stream>>>(q, k, v, ws, out);
}